// Round 8
// baseline (130.658 us; speedup 1.0000x reference)
//
#include <hip/hip_runtime.h>
#include <hip/hip_bf16.h>

// RGCN layer (R=8, B=4, N=1024, I=O=64, NB=4) on MI355X.
//
// Slot folding: out[o] = relu(bias[o] + sum_{j=9o..9o+8} concat[j]).
// Channel c of relation r -> o=(64r+c)/9, slot s=(r+c)/9 in [0,8).
// Folded weights w~[i][s]; slot read-back s = o - 7r.
//
//  prep_kernel : 288 blocks; w~ fold; x~[rb][n][8] f32 via MFMA; self blocks
//                -> selfP[b][n][8]; zeroes deg.
//  agg_kernel  : 1024 blocks x 256 thr (4/CU, ~50 VGPR -> no spill).
//                Block=(rb, 128-row m-panel, 256-col n-panel). THREAD OWNS ONE
//                COLUMN: acc[8] regs, depth-16 scalar-int prefetch, 8 fmaf/row,
//                NO main-loop barriers, NO cross-wave acc reduce (direct 32B
//                coalesced store to aggP). deg byte-packed in LDS (33KB),
//                u32-lane tail sum, exact-int atomicAdd (deterministic).
//  out_kernel  : out[o] = relu(bias + sum_c term(r1) + [r2!=r1] sum_c term(r2)),
//                term(r) = (sum of 8 mq-partials)/(deg+eps); r==8 -> selfP.

#define NN 1024
#define EPSK 1e-7f

typedef __bf16 bf16x8 __attribute__((ext_vector_type(8)));
typedef float f32x4 __attribute__((ext_vector_type(4)));

__device__ __forceinline__ unsigned short f2bf(float f) {
  union { float f; unsigned int u; } v; v.f = f;
  return (unsigned short)((v.u + 0x7FFFu + ((v.u >> 16) & 1u)) >> 16);
}

// ---------------------------------------------------------------------------
// prep: 288 blocks x 256 thr. bid<256: (r,b,chunk) -> x~ f32. bid>=256: self.
// ---------------------------------------------------------------------------
__global__ __launch_bounds__(256) void prep_kernel(
    const float* __restrict__ feat,    // [4,1024,64]
    const float* __restrict__ weight,  // [4,64,64]
    const float* __restrict__ Wo,      // [64,64]
    const float* __restrict__ wcmp,    // [8,4]
    float* __restrict__ xf,            // [32][1024][8] f32
    float* __restrict__ selfP,         // [4][1024][8] f32
    float* __restrict__ deg)           // [32][1024] f32
{
  __shared__ __align__(16) unsigned short featL[128 * 72];  // [n][i] bf16
  __shared__ __align__(16) float wTf[64 * 65];              // [c][i] f32
  __shared__ __align__(16) unsigned short wfold[16 * 72];   // [s][i] bf16
  __shared__ __align__(16) float stg[128 * 8];              // [n][s] f32 bounce

  const int bid = blockIdx.x;
  const int t = threadIdx.x;
  const bool isSelf = bid >= 256;
  int r, b, chunk;
  if (!isSelf) { r = bid >> 5; b = (bid >> 3) & 3; chunk = bid & 7; }
  else { const int s2 = bid - 256; b = s2 >> 3; chunk = s2 & 7; r = 8; }
  const int n0 = chunk << 7;

  // zero deg (stream-ordered before agg's atomics)
  if (bid < 32) {
    for (int k = t; k < NN; k += 256) deg[bid * NN + k] = 0.0f;
  }

  // stage features chunk [128 n][64 i] -> bf16 LDS
  const float* fsrc = feat + ((size_t)(b * NN + n0)) * 64;
  #pragma unroll
  for (int p = 0; p < 8; ++p) {
    const int idx = p * 256 + t;
    const int row = idx >> 4, c4 = idx & 15;
    const float4 v = *reinterpret_cast<const float4*>(fsrc + row * 64 + c4 * 4);
    ushort4 u;
    u.x = f2bf(v.x); u.y = f2bf(v.y); u.z = f2bf(v.z); u.w = f2bf(v.w);
    *reinterpret_cast<ushort4*>(&featL[row * 72 + c4 * 4]) = u;
  }

  // wTf[c][i] = w_full[i][c] (relation) or Wo[i][c] (self)
  if (!isSelf) {
    const float wc0 = wcmp[r * 4 + 0], wc1 = wcmp[r * 4 + 1];
    const float wc2 = wcmp[r * 4 + 2], wc3 = wcmp[r * 4 + 3];
    #pragma unroll
    for (int jj = 0; jj < 16; ++jj) {
      const int e = jj * 256 + t;
      const int i = e >> 6, c = e & 63;
      wTf[c * 65 + i] = wc0 * weight[i * 64 + c] + wc1 * weight[4096 + i * 64 + c] +
                        wc2 * weight[8192 + i * 64 + c] + wc3 * weight[12288 + i * 64 + c];
    }
  } else {
    #pragma unroll
    for (int jj = 0; jj < 16; ++jj) {
      const int e = jj * 256 + t;
      const int i = e >> 6, c = e & 63;
      wTf[c * 65 + i] = Wo[i * 64 + c];
    }
  }
  __syncthreads();

  // fold: wfold[s][i] = sum_{c : (r+c)/9 == s} wTf[c][i]; rows 8..15 zero
  #pragma unroll
  for (int jj = 0; jj < 4; ++jj) {
    const int e = jj * 256 + t;
    const int s = e >> 6, i = e & 63;
    float sum = 0.f;
    if (s < 8) {
      const int c0 = 9 * s - r;
      const int clo = c0 < 0 ? 0 : c0;
      const int chi = (c0 + 8 > 63) ? 63 : c0 + 8;
      for (int c = clo; c <= chi; ++c) sum += wTf[c * 65 + i];
    }
    wfold[s * 72 + i] = f2bf(sum);
  }
  __syncthreads();

  const int w = t >> 6, lane = t & 63;
  const int li = lane & 15, lg = lane >> 4;

  // MFMA: D[slot][n] = sum_i wfold[slot][i] * featL[n][i]
  f32x4 acc0 = {0.f, 0.f, 0.f, 0.f}, acc1 = {0.f, 0.f, 0.f, 0.f};
  #pragma unroll
  for (int ks = 0; ks < 2; ++ks) {
    const int kof = ks * 32 + lg * 8;
    const bf16x8 af = __builtin_bit_cast(bf16x8,
        *reinterpret_cast<const uint4*>(&wfold[li * 72 + kof]));
    const bf16x8 b0 = __builtin_bit_cast(bf16x8,
        *reinterpret_cast<const uint4*>(&featL[((2 * w + 0) * 16 + li) * 72 + kof]));
    const bf16x8 b1 = __builtin_bit_cast(bf16x8,
        *reinterpret_cast<const uint4*>(&featL[((2 * w + 1) * 16 + li) * 72 + kof]));
    acc0 = __builtin_amdgcn_mfma_f32_16x16x32_bf16(af, b0, acc0, 0, 0, 0);
    acc1 = __builtin_amdgcn_mfma_f32_16x16x32_bf16(af, b1, acc1, 0, 0, 0);
  }

  // lane holds D[slot=lg*4+qq][n=tile*16+li]; slots >=8 are zero -> drop
  if (lg < 2) {
    #pragma unroll
    for (int qq = 0; qq < 4; ++qq) {
      const int s = lg * 4 + qq;
      stg[((2 * w + 0) * 16 + li) * 8 + s] = acc0[qq];
      stg[((2 * w + 1) * 16 + li) * 8 + s] = acc1[qq];
    }
  }
  __syncthreads();
  // coalesced copy out: 4 KB = 256 thr x 16 B
  {
    float* dstF = isSelf ? (selfP + ((size_t)(b * NN + n0)) * 8)
                         : (xf + ((size_t)((r * 4 + b) * NN + n0)) * 8);
    *reinterpret_cast<float4*>(dstF + t * 4) =
        *reinterpret_cast<const float4*>(&stg[t * 4]);
  }
}

// ---------------------------------------------------------------------------
// agg: 1024 blocks x 256 thr (4/CU). Block=(rb, mq 128 rows, nq 256 cols).
// Thread owns ONE column. No main-loop barriers. ~50 VGPR.
// ---------------------------------------------------------------------------
#define BODY(PK, K)                                                             \
  {                                                                             \
    const int cur_ = PK;                                                        \
    const int ml_ = (g << 4) + (K);                                             \
    if (g < 7) {                                                                \
      PK = asrc[(ml_ + 16) << 10];                                              \
    }                                                                           \
    pk |= ((unsigned int)cur_) << (8 * ((K) & 3));                              \
    const float a_ = (float)cur_;                                               \
    const float4 xlo_ = *reinterpret_cast<const float4*>(&xsL[ml_ * 8]);        \
    const float4 xhi_ = *reinterpret_cast<const float4*>(&xsL[ml_ * 8 + 4]);    \
    acc0 = fmaf(a_, xlo_.x, acc0);                                              \
    acc1 = fmaf(a_, xlo_.y, acc1);                                              \
    acc2 = fmaf(a_, xlo_.z, acc2);                                              \
    acc3 = fmaf(a_, xlo_.w, acc3);                                              \
    acc4 = fmaf(a_, xhi_.x, acc4);                                              \
    acc5 = fmaf(a_, xhi_.y, acc5);                                              \
    acc6 = fmaf(a_, xhi_.z, acc6);                                              \
    acc7 = fmaf(a_, xhi_.w, acc7);                                              \
    if (((K) & 3) == 3) {                                                       \
      degL[((g << 2) + ((K) >> 2)) * 257 + t] = pk;                             \
      pk = 0u;                                                                  \
    }                                                                           \
  }

__global__ __launch_bounds__(256, 4) void agg_kernel(
    const int* __restrict__ adj,    // [32][1024][1024]
    const float* __restrict__ xf,   // [32][1024][8] f32
    float* __restrict__ aggP,       // [8 mq][32 rb][1024 n][8 s] f32
    float* __restrict__ deg)        // [32][1024] f32
{
  __shared__ __align__(16) float xsL[128 * 8];             // x~ panel, 4 KB
  __shared__ __align__(16) unsigned int degL[32 * 257];    // byte-packed, 33 KB

  const int bid = blockIdx.x;
  const int rb = bid >> 5, mq = (bid >> 2) & 7, nq = bid & 3;
  const int m0 = mq << 7, n0 = nq << 8;
  const int t = threadIdx.x;

  const int* asrc = adj + (((size_t)rb) << 20) + (((size_t)m0) << 10) + n0 + t;

  // depth-16 prefetch of this thread's column, rows 0..15 (issued first)
  int P0  = asrc[0 << 10];
  int P1  = asrc[1 << 10];
  int P2  = asrc[2 << 10];
  int P3  = asrc[3 << 10];
  int P4  = asrc[4 << 10];
  int P5  = asrc[5 << 10];
  int P6  = asrc[6 << 10];
  int P7  = asrc[7 << 10];
  int P8  = asrc[8 << 10];
  int P9  = asrc[9 << 10];
  int P10 = asrc[10 << 10];
  int P11 = asrc[11 << 10];
  int P12 = asrc[12 << 10];
  int P13 = asrc[13 << 10];
  int P14 = asrc[14 << 10];
  int P15 = asrc[15 << 10];

  // stage x~ rows [m0, m0+128): 4 KB
  {
    const float* xs = xf + ((size_t)(rb * NN + m0)) * 8;
    *reinterpret_cast<float4*>(&xsL[t * 4]) =
        *reinterpret_cast<const float4*>(xs + t * 4);
  }

  float acc0 = 0.f, acc1 = 0.f, acc2 = 0.f, acc3 = 0.f;
  float acc4 = 0.f, acc5 = 0.f, acc6 = 0.f, acc7 = 0.f;

  __syncthreads();  // xsL ready

  unsigned int pk = 0u;
  #pragma unroll 1
  for (int g = 0; g < 8; ++g) {
    BODY(P0, 0)  BODY(P1, 1)  BODY(P2, 2)  BODY(P3, 3)
    BODY(P4, 4)  BODY(P5, 5)  BODY(P6, 6)  BODY(P7, 7)
    BODY(P8, 8)  BODY(P9, 9)  BODY(P10, 10) BODY(P11, 11)
    BODY(P12, 12) BODY(P13, 13) BODY(P14, 14) BODY(P15, 15)
  }

  // acc writeout: thread owns column n0+t -> 32B contiguous, coalesced
  {
    float* dst = aggP + ((size_t)((mq * 32 + rb) * NN + n0 + t)) * 8;
    *reinterpret_cast<float4*>(dst) = make_float4(acc0, acc1, acc2, acc3);
    *reinterpret_cast<float4*>(dst + 4) = make_float4(acc4, acc5, acc6, acc7);
  }

  __syncthreads();  // degL complete

  // deg tail: thread t<128 owns row m0+t. u32-lane summation trick:
  // sum 256 u32s in two halves (byte-lanes <=128 each), extract own byte.
  if (t < 128) {
    const unsigned int* src = &degL[(t >> 2) * 257];
    const int sh = 8 * (t & 3);
    uint4 sa = make_uint4(0u, 0u, 0u, 0u), sb = make_uint4(0u, 0u, 0u, 0u);
    #pragma unroll
    for (int c4 = 0; c4 < 32; ++c4) {
      const uint4 v = *reinterpret_cast<const uint4*>(src + c4 * 4);
      sa.x += v.x; sa.y += v.y; sa.z += v.z; sa.w += v.w;
    }
    #pragma unroll
    for (int c4 = 32; c4 < 64; ++c4) {
      const uint4 v = *reinterpret_cast<const uint4*>(src + c4 * 4);
      sb.x += v.x; sb.y += v.y; sb.z += v.z; sb.w += v.w;
    }
    const unsigned int hA = sa.x + sa.y;  // byte-lanes <=64
    const unsigned int hB = sa.z + sa.w;
    const unsigned int hC = sb.x + sb.y;
    const unsigned int hD = sb.z + sb.w;
    const int sum = (int)((hA >> sh) & 0xFFu) + (int)((hB >> sh) & 0xFFu) +
                    (int)((hC >> sh) & 0xFFu) + (int)((hD >> sh) & 0xFFu);
    atomicAdd(&deg[rb * NN + m0 + t], (float)sum);  // exact ints, deterministic
  }
}

// ---------------------------------------------------------------------------
// epilogue: combine 8 mq-partials + self, divide by deg, bias, relu
// ---------------------------------------------------------------------------
__global__ __launch_bounds__(256) void out_kernel(
    const float* __restrict__ aggP,   // [8][32][1024][8]
    const float* __restrict__ selfP,  // [4][1024][8]
    const float* __restrict__ deg,    // [32][1024]
    const float* __restrict__ bias, float* __restrict__ out)
{
  const int gid = blockIdx.x * 256 + threadIdx.x;
  const int o = gid & 63;
  const int n = (gid >> 6) & 1023;
  const int b = gid >> 16;

  const int r1 = (9 * o) >> 6;
  const int r2 = (9 * o + 8) >> 6;

  float acc = bias[o];
  #pragma unroll
  for (int pass = 0; pass < 2; ++pass) {
    const int r = pass ? r2 : r1;
    if (pass && r2 == r1) break;
    float v;
    if (r < 8) {
      const int s = o - 7 * r;
      const size_t base = (((size_t)(r * 4 + b)) * NN + n) * 8 + s;
      float sum = 0.f;
      #pragma unroll
      for (int c = 0; c < 8; ++c) sum += aggP[base + (size_t)c * 262144];
      v = sum / (deg[(r * 4 + b) * NN + n] + EPSK);
    } else {
      v = selfP[((size_t)(b * NN + n)) * 8 + (o - 56)];
    }
    acc += v;
  }
  out[gid] = fmaxf(acc, 0.0f);
}

extern "C" void kernel_launch(void* const* d_in, const int* in_sizes, int n_in,
                              void* d_out, int out_size, void* d_ws, size_t ws_size,
                              hipStream_t stream) {
  const float* feat   = (const float*)d_in[0];
  const int*   adj    = (const int*)d_in[1];
  const float* weight = (const float*)d_in[2];
  const float* Wo     = (const float*)d_in[3];
  const float* wcmp   = (const float*)d_in[4];
  const float* bias   = (const float*)d_in[5];
  float* out = (float*)d_out;

  // ws: x~ f32 (1 MiB) | selfP (128 KiB) | aggP (8 MiB) | deg (128 KiB)
  char* ws = (char*)d_ws;
  float* xf    = (float*)(ws);
  float* selfP = (float*)(ws + 1048576u);
  float* aggP  = (float*)(ws + 1048576u + 131072u);
  float* deg   = (float*)(ws + 1048576u + 131072u + 8388608u);

  prep_kernel<<<dim3(288), dim3(256), 0, stream>>>(feat, weight, Wo, wcmp, xf, selfP, deg);
  agg_kernel<<<dim3(1024), dim3(256), 0, stream>>>(adj, xf, aggP, deg);
  out_kernel<<<dim3(1024), dim3(256), 0, stream>>>(aggP, selfP, deg, bias, out);
}

// Round 9
// 35.231 us; speedup vs baseline: 3.7086x; 3.7086x over previous
//
#include <hip/hip_runtime.h>
#include <hip/hip_bf16.h>

// RGCN layer (R=8, B=4, N=1024, I=O=64, NB=4) on MI355X.  [R5 revert — best measured]
//
// Slot folding: out[o] = relu(bias[o] + sum_{j=9o..9o+8} concat[j]).
// Channel c of relation r lands at o=(64r+c)/9 -> slot s=(r+c)/9 in [0,8).
// Per-relation folded weights w~[i][s] (8 slots). Slot read-back: s = o - 7r.
//
//  prep_kernel : 288 blocks; w~ fold; x~[rb][n][8] f32 via MFMA (bf16 in, f32
//                out, coalesced via LDS bounce); self blocks -> selfP[b][n][8];
//                zeroes deg.
//  agg_kernel  : 512 blocks x 256 thr (2/CU), VALU streaming — NO main-loop
//                barriers, no transpose, no MFMA. Block=(rb, n-quarter 256,
//                m-quarter 256). Thread (tm,tn): int4 adj loads (contiguous
//                1KB/row-group), 32 v_fmac into acc[4n][8s]; deg partial via
//                1 ds_write/m + end reduce (exact int-in-f32 atomics).
//                Partials -> aggP[mq][rb][n][8] (non-atomic, deterministic).
//  out_kernel  : out[o] = relu(bias + sum_mq term(r1) + [r2!=r1] sum_mq term(r2)),
//                term(r) = aggP[.]/(deg+eps), r==8 -> selfP.

#define NN 1024
#define EPSK 1e-7f

typedef __bf16 bf16x8 __attribute__((ext_vector_type(8)));
typedef float f32x4 __attribute__((ext_vector_type(4)));

__device__ __forceinline__ unsigned short f2bf(float f) {
  union { float f; unsigned int u; } v; v.f = f;
  return (unsigned short)((v.u + 0x7FFFu + ((v.u >> 16) & 1u)) >> 16);
}

// ---------------------------------------------------------------------------
// prep: 288 blocks x 256 thr. bid<256: (r,b,chunk) -> x~ f32. bid>=256: self.
// ---------------------------------------------------------------------------
__global__ __launch_bounds__(256) void prep_kernel(
    const float* __restrict__ feat,    // [4,1024,64]
    const float* __restrict__ weight,  // [4,64,64]
    const float* __restrict__ Wo,      // [64,64]
    const float* __restrict__ wcmp,    // [8,4]
    float* __restrict__ xf,            // [32][1024][8] f32
    float* __restrict__ selfP,         // [4][1024][8] f32
    float* __restrict__ deg)           // [32][1024] f32
{
  __shared__ __align__(16) unsigned short featL[128 * 72];  // [n][i] bf16
  __shared__ __align__(16) float wTf[64 * 65];              // [c][i] f32
  __shared__ __align__(16) unsigned short wfold[16 * 72];   // [s][i] bf16
  __shared__ __align__(16) float stg[128 * 8];              // [n][s] f32 bounce

  const int bid = blockIdx.x;
  const int t = threadIdx.x;
  const bool isSelf = bid >= 256;
  int r, b, chunk;
  if (!isSelf) { r = bid >> 5; b = (bid >> 3) & 3; chunk = bid & 7; }
  else { const int s2 = bid - 256; b = s2 >> 3; chunk = s2 & 7; r = 8; }
  const int n0 = chunk << 7;

  // zero deg (stream-ordered before agg)
  if (bid < 32) {
    for (int k = t; k < NN; k += 256) deg[bid * NN + k] = 0.0f;
  }

  // stage features chunk [128 n][64 i] -> bf16 LDS
  const float* fsrc = feat + ((size_t)(b * NN + n0)) * 64;
  #pragma unroll
  for (int p = 0; p < 8; ++p) {
    const int idx = p * 256 + t;
    const int row = idx >> 4, c4 = idx & 15;
    const float4 v = *reinterpret_cast<const float4*>(fsrc + row * 64 + c4 * 4);
    ushort4 u;
    u.x = f2bf(v.x); u.y = f2bf(v.y); u.z = f2bf(v.z); u.w = f2bf(v.w);
    *reinterpret_cast<ushort4*>(&featL[row * 72 + c4 * 4]) = u;
  }

  // wTf[c][i] = w_full[i][c] (relation) or Wo[i][c] (self)
  if (!isSelf) {
    const float wc0 = wcmp[r * 4 + 0], wc1 = wcmp[r * 4 + 1];
    const float wc2 = wcmp[r * 4 + 2], wc3 = wcmp[r * 4 + 3];
    #pragma unroll
    for (int jj = 0; jj < 16; ++jj) {
      const int e = jj * 256 + t;
      const int i = e >> 6, c = e & 63;
      wTf[c * 65 + i] = wc0 * weight[i * 64 + c] + wc1 * weight[4096 + i * 64 + c] +
                        wc2 * weight[8192 + i * 64 + c] + wc3 * weight[12288 + i * 64 + c];
    }
  } else {
    #pragma unroll
    for (int jj = 0; jj < 16; ++jj) {
      const int e = jj * 256 + t;
      const int i = e >> 6, c = e & 63;
      wTf[c * 65 + i] = Wo[i * 64 + c];
    }
  }
  __syncthreads();

  // fold: wfold[s][i] = sum_{c : (r+c)/9 == s} wTf[c][i]; rows 8..15 zero
  #pragma unroll
  for (int jj = 0; jj < 4; ++jj) {
    const int e = jj * 256 + t;
    const int s = e >> 6, i = e & 63;
    float sum = 0.f;
    if (s < 8) {
      const int c0 = 9 * s - r;
      const int clo = c0 < 0 ? 0 : c0;
      const int chi = (c0 + 8 > 63) ? 63 : c0 + 8;
      for (int c = clo; c <= chi; ++c) sum += wTf[c * 65 + i];
    }
    wfold[s * 72 + i] = f2bf(sum);
  }
  __syncthreads();

  const int w = t >> 6, lane = t & 63;
  const int li = lane & 15, lg = lane >> 4;

  // MFMA: D[slot][n] = sum_i wfold[slot][i] * featL[n][i]
  f32x4 acc0 = {0.f, 0.f, 0.f, 0.f}, acc1 = {0.f, 0.f, 0.f, 0.f};
  #pragma unroll
  for (int ks = 0; ks < 2; ++ks) {
    const int kof = ks * 32 + lg * 8;
    const bf16x8 af = __builtin_bit_cast(bf16x8,
        *reinterpret_cast<const uint4*>(&wfold[li * 72 + kof]));
    const bf16x8 b0 = __builtin_bit_cast(bf16x8,
        *reinterpret_cast<const uint4*>(&featL[((2 * w + 0) * 16 + li) * 72 + kof]));
    const bf16x8 b1 = __builtin_bit_cast(bf16x8,
        *reinterpret_cast<const uint4*>(&featL[((2 * w + 1) * 16 + li) * 72 + kof]));
    acc0 = __builtin_amdgcn_mfma_f32_16x16x32_bf16(af, b0, acc0, 0, 0, 0);
    acc1 = __builtin_amdgcn_mfma_f32_16x16x32_bf16(af, b1, acc1, 0, 0, 0);
  }

  // lane holds D[slot=lg*4+qq][n=tile*16+li]; slots >=8 are zero -> drop
  if (lg < 2) {
    #pragma unroll
    for (int qq = 0; qq < 4; ++qq) {
      const int s = lg * 4 + qq;
      stg[((2 * w + 0) * 16 + li) * 8 + s] = acc0[qq];
      stg[((2 * w + 1) * 16 + li) * 8 + s] = acc1[qq];
    }
  }
  __syncthreads();
  // coalesced copy: 4 KB = 256 thr x 16 B
  {
    float* dstF = isSelf ? (selfP + ((size_t)(b * NN + n0)) * 8)
                         : (xf + ((size_t)((r * 4 + b) * NN + n0)) * 8);
    *reinterpret_cast<float4*>(dstF + t * 4) =
        *reinterpret_cast<const float4*>(&stg[t * 4]);
  }
}

// ---------------------------------------------------------------------------
// agg: 512 blocks x 256 thr (2/CU). Block=(rb, nq, mq). Pure VALU streaming.
// ---------------------------------------------------------------------------
__global__ __launch_bounds__(256) void agg_kernel(
    const int* __restrict__ adj,    // [32][1024][1024]
    const float* __restrict__ xf,   // [32][1024][8] f32
    float* __restrict__ aggP,       // [4 mq][32 rb][1024 n][8 s] f32
    float* __restrict__ deg)        // [32][1024] f32
{
  __shared__ __align__(16) float xsL[256 * 8];    // x~ panel (m-quarter), 8 KB
  __shared__ __align__(16) float degL[256 * 66];  // deg partials; tail reused

  const int bid = blockIdx.x;
  const int rb = bid >> 4, mq = (bid >> 2) & 3, nq = bid & 3;
  const int t = threadIdx.x;
  const int tm = t >> 6, tn = t & 63;  // wave index = m-phase; lane = n-quad
  const int mbase = mq << 8, nbase = nq << 8;

  // stage x~ panel: 8 KB contiguous
  {
    const float* xs = xf + ((size_t)(rb * NN + mbase)) * 8;
    *reinterpret_cast<float4*>(&xsL[t * 8]) = *reinterpret_cast<const float4*>(xs + t * 8);
    *reinterpret_cast<float4*>(&xsL[t * 8 + 4]) = *reinterpret_cast<const float4*>(xs + t * 8 + 4);
  }

  const int* asrc = adj + (((size_t)rb) << 20) + ((size_t)mbase << 10) + nbase + (tn << 2);

  float acc[4][8];
  #pragma unroll
  for (int j = 0; j < 4; ++j)
    #pragma unroll
    for (int s = 0; s < 8; ++s) acc[j][s] = 0.f;

  __syncthreads();  // xsL ready

  // m-loop: i=0..63, m_local = 4i + tm (rolling contiguous 4-row window/block)
  int4 buf0 = *reinterpret_cast<const int4*>(asrc + ((size_t)(0 * 4 + tm) << 10));
  int4 buf1 = *reinterpret_cast<const int4*>(asrc + ((size_t)(1 * 4 + tm) << 10));
  int4 buf2 = *reinterpret_cast<const int4*>(asrc + ((size_t)(2 * 4 + tm) << 10));
  int4 buf3 = *reinterpret_cast<const int4*>(asrc + ((size_t)(3 * 4 + tm) << 10));

#define AGG_BODY(BUF, I)                                                        \
  {                                                                             \
    const int4 cur_ = BUF;                                                      \
    const int ml_ = ((I) << 2) + tm;                                            \
    if ((I) < 60) {                                                             \
      BUF = *reinterpret_cast<const int4*>(asrc + ((size_t)(ml_ + 16) << 10));  \
    }                                                                           \
    const float a0_ = (float)cur_.x, a1_ = (float)cur_.y;                       \
    const float a2_ = (float)cur_.z, a3_ = (float)cur_.w;                       \
    degL[ml_ * 66 + tn] = (float)(cur_.x + cur_.y + cur_.z + cur_.w);           \
    const float4 xlo_ = *reinterpret_cast<const float4*>(&xsL[ml_ * 8]);        \
    const float4 xhi_ = *reinterpret_cast<const float4*>(&xsL[ml_ * 8 + 4]);    \
    const float xs_[8] = {xlo_.x, xlo_.y, xlo_.z, xlo_.w,                       \
                          xhi_.x, xhi_.y, xhi_.z, xhi_.w};                      \
    _Pragma("unroll")                                                           \
    for (int s_ = 0; s_ < 8; ++s_) {                                            \
      acc[0][s_] = fmaf(a0_, xs_[s_], acc[0][s_]);                              \
      acc[1][s_] = fmaf(a1_, xs_[s_], acc[1][s_]);                              \
      acc[2][s_] = fmaf(a2_, xs_[s_], acc[2][s_]);                              \
      acc[3][s_] = fmaf(a3_, xs_[s_], acc[3][s_]);                              \
    }                                                                           \
  }

  for (int ib = 0; ib < 16; ++ib) {
    AGG_BODY(buf0, ib * 4 + 0);
    AGG_BODY(buf1, ib * 4 + 1);
    AGG_BODY(buf2, ib * 4 + 2);
    AGG_BODY(buf3, ib * 4 + 3);
  }
#undef AGG_BODY

  __syncthreads();

  // deg reduce: thread t owns m_local=t; sum 64 tn-partials; exact int in f32
  {
    float s = 0.f;
    #pragma unroll
    for (int k = 0; k < 32; ++k) {
      const float2 v = *reinterpret_cast<const float2*>(&degL[t * 66 + 2 * k]);
      s += v.x + v.y;
    }
    atomicAdd(&deg[rb * NN + mbase + t], s);
  }
  __syncthreads();

  // acc reduce across tm via LDS (reuse degL region, stride 36 to spread banks)
  float* accL = degL;
  #pragma unroll
  for (int j = 0; j < 4; ++j) {
    *reinterpret_cast<float4*>(&accL[t * 36 + j * 8]) =
        make_float4(acc[j][0], acc[j][1], acc[j][2], acc[j][3]);
    *reinterpret_cast<float4*>(&accL[t * 36 + j * 8 + 4]) =
        make_float4(acc[j][4], acc[j][5], acc[j][6], acc[j][7]);
  }
  __syncthreads();
  {
    const int nl = t;                 // n_local 0..255
    const int tn2 = nl >> 2, j2 = nl & 3;
    float o8[8];
    #pragma unroll
    for (int s = 0; s < 8; ++s) o8[s] = 0.f;
    #pragma unroll
    for (int tm2 = 0; tm2 < 4; ++tm2) {
      const int base = (tm2 * 64 + tn2) * 36 + j2 * 8;
      const float4 lo = *reinterpret_cast<const float4*>(&accL[base]);
      const float4 hi = *reinterpret_cast<const float4*>(&accL[base + 4]);
      o8[0] += lo.x; o8[1] += lo.y; o8[2] += lo.z; o8[3] += lo.w;
      o8[4] += hi.x; o8[5] += hi.y; o8[6] += hi.z; o8[7] += hi.w;
    }
    float* dst = aggP + (((size_t)(mq * 32 + rb)) * NN + nbase + nl) * 8;
    *reinterpret_cast<float4*>(dst) = make_float4(o8[0], o8[1], o8[2], o8[3]);
    *reinterpret_cast<float4*>(dst + 4) = make_float4(o8[4], o8[5], o8[6], o8[7]);
  }
}

// ---------------------------------------------------------------------------
// epilogue: combine 4 mq-partials + self, divide by deg, bias, relu
// ---------------------------------------------------------------------------
__global__ __launch_bounds__(256) void out_kernel(
    const float* __restrict__ aggP,   // [4][32][1024][8]
    const float* __restrict__ selfP,  // [4][1024][8]
    const float* __restrict__ deg,    // [32][1024]
    const float* __restrict__ bias, float* __restrict__ out)
{
  const int gid = blockIdx.x * 256 + threadIdx.x;
  const int o = gid & 63;
  const int n = (gid >> 6) & 1023;
  const int b = gid >> 16;

  const int r1 = (9 * o) >> 6;
  const int r2 = (9 * o + 8) >> 6;

  float acc = bias[o];
  #pragma unroll
  for (int pass = 0; pass < 2; ++pass) {
    const int r = pass ? r2 : r1;
    if (pass && r2 == r1) break;
    float v;
    if (r < 8) {
      const int s = o - 7 * r;
      const size_t base = (((size_t)(r * 4 + b)) * NN + n) * 8 + s;
      v = aggP[base] + aggP[base + 262144] + aggP[base + 524288] + aggP[base + 786432];
      v /= (deg[(r * 4 + b) * NN + n] + EPSK);
    } else {
      v = selfP[((size_t)(b * NN + n)) * 8 + (o - 56)];
    }
    acc += v;
  }
  out[gid] = fmaxf(acc, 0.0f);
}

extern "C" void kernel_launch(void* const* d_in, const int* in_sizes, int n_in,
                              void* d_out, int out_size, void* d_ws, size_t ws_size,
                              hipStream_t stream) {
  const float* feat   = (const float*)d_in[0];
  const int*   adj    = (const int*)d_in[1];
  const float* weight = (const float*)d_in[2];
  const float* Wo     = (const float*)d_in[3];
  const float* wcmp   = (const float*)d_in[4];
  const float* bias   = (const float*)d_in[5];
  float* out = (float*)d_out;

  // ws: x~ f32 (1 MiB) | selfP (128 KiB) | aggP (4 MiB) | deg (128 KiB)
  char* ws = (char*)d_ws;
  float* xf    = (float*)(ws);
  float* selfP = (float*)(ws + 1048576u);
  float* aggP  = (float*)(ws + 1048576u + 131072u);
  float* deg   = (float*)(ws + 1048576u + 131072u + 4194304u);

  prep_kernel<<<dim3(288), dim3(256), 0, stream>>>(feat, weight, Wo, wcmp, xf, selfP, deg);
  agg_kernel<<<dim3(512), dim3(256), 0, stream>>>(adj, xf, aggP, deg);
  out_kernel<<<dim3(1024), dim3(256), 0, stream>>>(aggP, selfP, deg, bias, out);
}